// Round 1
// baseline (1509.046 us; speedup 1.0000x reference)
//
#include <hip/hip_runtime.h>
#include <hip/hip_bf16.h>
#include <cstdint>
#include <cstddef>

#define NEG_SLOPE 0.2f
#define HD 128   // hidden / feature dim
#define ED 50    // edge attr dim

static inline int ceil_div(int a, int b){ return (a + b - 1) / b; }

// ---------------- init: zero accumulators ----------------
__global__ void k_init(int* __restrict__ counts, float* __restrict__ pool_sum,
                       float* __restrict__ pool_cnt, float* __restrict__ al_e_sum,
                       int n, int g)
{
  int i = blockIdx.x * blockDim.x + threadIdx.x;
  int stride = gridDim.x * blockDim.x;
  for (int idx = i; idx < n; idx += stride) counts[idx] = 0;
  if (i < g) { pool_sum[i] = 0.f; pool_cnt[i] = 0.f; }
  if (i < 2) al_e_sum[i] = 0.f;
}

// ---------------- we_vec[l] = We_l @ ae_l (ED-vector) ----------------
__global__ void k_wevec(const float* __restrict__ We1, const float* __restrict__ ae1,
                        const float* __restrict__ We2, const float* __restrict__ ae2,
                        float* __restrict__ we_vec /*2*64*/)
{
  int l = blockIdx.x, d = threadIdx.x;
  const float* We = l ? We2 : We1;
  const float* ae = l ? ae2 : ae1;
  if (d < ED) {
    float s = 0.f;
    for (int k = 0; k < HD; ++k) s += We[d * HD + k] * ae[k];
    we_vec[l * 64 + d] = s;
  }
}

// ---------------- al_e[e] = edge_attr[e] . we_vec   (both layers, one pass) ----------------
__global__ __launch_bounds__(256) void k_edge_ale(
    const float* __restrict__ ea, const float* __restrict__ we_vec,
    float* __restrict__ al_e1, float* __restrict__ al_e2,
    float* __restrict__ al_e_sum, int E)
{
  __shared__ float acc1[256], acc2[256];
  __shared__ float wv1[64], wv2[64];
  int tid = threadIdx.x;
  if (tid < 64) { wv1[tid] = we_vec[tid]; wv2[tid] = we_vec[64 + tid]; }
  acc1[tid] = 0.f; acc2[tid] = 0.f;
  __syncthreads();

  int e0 = blockIdx.x * 256;
  int cnt = min(256, E - e0);
  if (cnt <= 0) return;             // uniform per block
  int elems = cnt * ED;
  const float* base = ea + (size_t)e0 * ED;
  for (int i = tid; i < elems; i += 256) {
    float v = base[i];
    int le = i / ED;
    int d  = i - le * ED;
    atomicAdd(&acc1[le], v * wv1[d]);
    atomicAdd(&acc2[le], v * wv2[d]);
  }
  __syncthreads();
  float a1 = 0.f, a2 = 0.f;
  if (tid < cnt) {
    a1 = acc1[tid]; a2 = acc2[tid];
    al_e1[e0 + tid] = a1; al_e2[e0 + tid] = a2;
  }
  __syncthreads();
  acc1[tid] = a1; acc2[tid] = a2;
  __syncthreads();
  for (int s = 128; s; s >>= 1) {
    if (tid < s) { acc1[tid] += acc1[tid + s]; acc2[tid] += acc2[tid + s]; }
    __syncthreads();
  }
  if (tid == 0) { atomicAdd(&al_e_sum[0], acc1[0]); atomicAdd(&al_e_sum[1], acc2[0]); }
}

// loop_e[l] = mean_e al_e[l][e]  (== mean(edge_attr) @ We @ ae)
__global__ void k_loop_e(const float* __restrict__ al_e_sum, float* __restrict__ loop_e, float invE)
{
  int t = threadIdx.x;
  if (t < 2) loop_e[t] = al_e_sum[t] * invE;
}

// ---------------- CSR build over dst ----------------
__global__ void k_count(const int* __restrict__ dst, int* __restrict__ counts, int E)
{
  int i = blockIdx.x * blockDim.x + threadIdx.x;
  int stride = gridDim.x * blockDim.x;
  for (; i < E; i += stride) atomicAdd(&counts[dst[i]], 1);
}

__global__ __launch_bounds__(1024) void k_scanA(const int* __restrict__ counts, int* __restrict__ tmp,
                                                int* __restrict__ chunk_sums, int n)
{
  __shared__ int sd[1024];
  int tid = threadIdx.x;
  int i = blockIdx.x * 1024 + tid;
  int v = (i < n) ? counts[i] : 0;
  sd[tid] = v;
  __syncthreads();
  for (int off = 1; off < 1024; off <<= 1) {
    int t = (tid >= off) ? sd[tid - off] : 0;
    __syncthreads();
    sd[tid] += t;
    __syncthreads();
  }
  if (i < n) tmp[i] = sd[tid] - v;   // exclusive
  if (tid == 1023) chunk_sums[blockIdx.x] = sd[1023];
}

__global__ void k_scanB(const int* __restrict__ chunk_sums, int* __restrict__ chunk_off,
                        int nchunks, int* __restrict__ row_off_end)
{
  if (threadIdx.x == 0) {
    int run = 0;
    for (int c = 0; c < nchunks; ++c) { chunk_off[c] = run; run += chunk_sums[c]; }
    *row_off_end = run;
  }
}

__global__ __launch_bounds__(1024) void k_scanC(const int* __restrict__ tmp, const int* __restrict__ chunk_off,
                                                int* __restrict__ row_off, int* __restrict__ cursor, int n)
{
  int i = blockIdx.x * 1024 + threadIdx.x;
  if (i < n) {
    int v = tmp[i] + chunk_off[blockIdx.x];
    row_off[i] = v;
    cursor[i] = v;
  }
}

__global__ void k_fill(const int* __restrict__ dst, int* __restrict__ cursor,
                       int* __restrict__ csr, int E)
{
  int i = blockIdx.x * blockDim.x + threadIdx.x;
  int stride = gridDim.x * blockDim.x;
  for (; i < E; i += stride) {
    int d = dst[i];
    int pos = atomicAdd(&cursor[d], 1);
    csr[pos] = i;
  }
}

// ---------------- C[M,128] = A[M,128] @ W[128,128], W staged in LDS ----------------
__global__ __launch_bounds__(256) void k_gemm128(const float* __restrict__ A,
                                                 const float* __restrict__ W,
                                                 float* __restrict__ C, int M)
{
  __shared__ float Wl[HD * HD];
  int tid = threadIdx.x;
  const float4* W4 = (const float4*)W;
  float4* Wl4 = (float4*)Wl;
  for (int i = tid; i < HD * HD / 4; i += 256) Wl4[i] = W4[i];
  __syncthreads();
  int j = tid & 127, rh = tid >> 7;
  int base = blockIdx.x * 16;
  for (int r = rh; r < 16; r += 2) {
    int row = base + r;
    if (row >= M) break;
    const float* xr = A + (size_t)row * HD;
    float acc = 0.f;
#pragma unroll
    for (int k = 0; k < HD; k += 4) {
      float4 xv = *(const float4*)(xr + k);
      acc = fmaf(xv.x, Wl[(k + 0) * HD + j], acc);
      acc = fmaf(xv.y, Wl[(k + 1) * HD + j], acc);
      acc = fmaf(xv.z, Wl[(k + 2) * HD + j], acc);
      acc = fmaf(xv.w, Wl[(k + 3) * HD + j], acc);
    }
    C[(size_t)row * HD + j] = acc;
  }
}

// ---------------- al_s[n] = h[n].as, al_d[n] = h[n].ad ----------------
__global__ void k_node_dots(const float* __restrict__ h, const float* __restrict__ a_s,
                            const float* __restrict__ a_d, float* __restrict__ al_s,
                            float* __restrict__ al_d, int n)
{
  int wave = threadIdx.x >> 6, lane = threadIdx.x & 63;
  int node = blockIdx.x * 4 + wave;
  if (node >= n) return;
  const float* hr = h + (size_t)node * HD;
  float v1 = hr[lane], v2 = hr[lane + 64];
  float ss = v1 * a_s[lane] + v2 * a_s[lane + 64];
  float dd = v1 * a_d[lane] + v2 * a_d[lane + 64];
#pragma unroll
  for (int o = 32; o; o >>= 1) { ss += __shfl_xor(ss, o); dd += __shfl_xor(dd, o); }
  if (lane == 0) { al_s[node] = ss; al_d[node] = dd; }
}

// ---------------- GAT aggregation: one wave per dst node ----------------
// FUSE=false: write o[n] = relu(agg + b)
// FUSE=true : t = relu(agg + b) . Wfc ; atomicAdd to pool accumulators (never materialize o)
template <bool FUSE>
__global__ __launch_bounds__(256) void k_agg(
    const int* __restrict__ row_off, const int* __restrict__ csr,
    const int* __restrict__ src,
    const float* __restrict__ al_s, const float* __restrict__ al_d,
    const float* __restrict__ al_e, const float* __restrict__ loop_e, int le_idx,
    const float* __restrict__ h, const float* __restrict__ bias,
    float* __restrict__ o,
    const float* __restrict__ Wfc, const int* __restrict__ batchv,
    float* __restrict__ pool_sum, float* __restrict__ pool_cnt,
    int n_nodes)
{
  int wave = threadIdx.x >> 6, lane = threadIdx.x & 63;
  int n = blockIdx.x * 4 + wave;
  if (n >= n_nodes) return;

  float led  = loop_e[le_idx];
  float ad_n = al_d[n];

  // self loop (src = dst = n), alphas are O(1): exp without max-shift is safe
  float a0 = al_s[n] + ad_n + led;
  a0 = a0 > 0.f ? a0 : NEG_SLOPE * a0;
  float w = __expf(a0);
  const float* hn = h + (size_t)n * HD;
  float acc1 = w * hn[lane];
  float acc2 = w * hn[lane + 64];
  float s = w;

  int k0 = row_off[n], k1 = row_off[n + 1];
  for (int k = k0; k < k1; ++k) {
    int e  = csr[k];
    int sn = src[e];
    float a = al_s[sn] + ad_n + al_e[e];
    a = a > 0.f ? a : NEG_SLOPE * a;
    float we = __expf(a);
    s += we;
    const float* hs = h + (size_t)sn * HD;
    acc1 += we * hs[lane];
    acc2 += we * hs[lane + 64];
  }

  float inv = 1.0f / s;
  float o1v = fmaxf(acc1 * inv + bias[lane], 0.f);
  float o2v = fmaxf(acc2 * inv + bias[lane + 64], 0.f);

  if (FUSE) {
    float t = o1v * Wfc[lane] + o2v * Wfc[lane + 64];
#pragma unroll
    for (int ofs = 32; ofs; ofs >>= 1) t += __shfl_xor(t, ofs);
    if (lane == 0) {
      int g = batchv[n];
      atomicAdd(&pool_sum[g], t);
      atomicAdd(&pool_cnt[g], 1.0f);
    }
  } else {
    float* orow = o + (size_t)n * HD;
    orow[lane] = o1v;
    orow[lane + 64] = o2v;
  }
}

// ---------------- finalize: out[g] = pool_sum/cnt + bfc ----------------
__global__ void k_final(const float* __restrict__ pool_sum, const float* __restrict__ pool_cnt,
                        const float* __restrict__ bfc, float* __restrict__ out, int g)
{
  int i = blockIdx.x * blockDim.x + threadIdx.x;
  if (i < g) out[i] = pool_sum[i] / fmaxf(pool_cnt[i], 1.f) + bfc[0];
}

// =====================================================================
extern "C" void kernel_launch(void* const* d_in, const int* in_sizes, int n_in,
                              void* d_out, int out_size, void* d_ws, size_t ws_size,
                              hipStream_t stream)
{
  const float* x       = (const float*)d_in[0];
  const int*   ei      = (const int*)d_in[1];
  const float* ea      = (const float*)d_in[2];
  const int*   batchv  = (const int*)d_in[3];
  const float* W1  = (const float*)d_in[4];
  const float* as1 = (const float*)d_in[5];
  const float* ad1 = (const float*)d_in[6];
  const float* We1 = (const float*)d_in[7];
  const float* ae1 = (const float*)d_in[8];
  const float* b1  = (const float*)d_in[9];
  const float* W2  = (const float*)d_in[10];
  const float* as2 = (const float*)d_in[11];
  const float* ad2 = (const float*)d_in[12];
  const float* We2 = (const float*)d_in[13];
  const float* ae2 = (const float*)d_in[14];
  const float* b2  = (const float*)d_in[15];
  const float* Wfc = (const float*)d_in[16];
  const float* bfc = (const float*)d_in[17];
  float* out = (float*)d_out;

  const int N = in_sizes[0] / HD;
  const int E = in_sizes[1] / 2;
  const int G = out_size;               // 256 graphs, OUT=1
  const int* src = ei;
  const int* dst = ei + E;

  // ---- carve workspace ----
  char* p = (char*)d_ws;
  auto alloc = [&](size_t bytes) -> void* {
    void* r = (void*)p;
    p += (bytes + 255) & ~(size_t)255;
    return r;
  };
  float* hA       = (float*)alloc((size_t)N * HD * 4);   // h1, then h2
  float* oB       = (float*)alloc((size_t)N * HD * 4);   // relu(gat1)
  float* al_e1    = (float*)alloc((size_t)E * 4);
  float* al_e2    = (float*)alloc((size_t)E * 4);
  float* al_s     = (float*)alloc((size_t)N * 4);
  float* al_d     = (float*)alloc((size_t)N * 4);
  int*   counts   = (int*)alloc((size_t)N * 4);          // then reused as cursor
  int*   row_off  = (int*)alloc((size_t)(N + 1) * 4);
  int*   tmp_scan = (int*)alloc((size_t)N * 4);
  int*   chunk_sums = (int*)alloc(64 * 4);
  int*   chunk_off  = (int*)alloc(64 * 4);
  int*   csr      = (int*)alloc((size_t)E * 4);
  float* we_vec   = (float*)alloc(2 * 64 * 4);
  float* al_e_sum = (float*)alloc(2 * 4);
  float* loop_e   = (float*)alloc(2 * 4);
  float* pool_sum = (float*)alloc((size_t)G * 4);
  float* pool_cnt = (float*)alloc((size_t)G * 4);
  (void)ws_size; (void)n_in;

  const int nchunks = ceil_div(N, 1024);

  // 1. zero accumulators
  k_init<<<ceil_div(N, 256), 256, 0, stream>>>(counts, pool_sum, pool_cnt, al_e_sum, N, G);
  // 2. we_vec for both layers
  k_wevec<<<2, 64, 0, stream>>>(We1, ae1, We2, ae2, we_vec);
  // 3. al_e for both layers in ONE pass over edge_attr (+ sums for self-loop mean)
  k_edge_ale<<<ceil_div(E, 256), 256, 0, stream>>>(ea, we_vec, al_e1, al_e2, al_e_sum, E);
  // 4. self-loop edge logits
  k_loop_e<<<1, 64, 0, stream>>>(al_e_sum, loop_e, 1.0f / (float)E);
  // 5-8. CSR build by dst
  k_count<<<2048, 256, 0, stream>>>(dst, counts, E);
  k_scanA<<<nchunks, 1024, 0, stream>>>(counts, tmp_scan, chunk_sums, N);
  k_scanB<<<1, 64, 0, stream>>>(chunk_sums, chunk_off, nchunks, &row_off[N]);
  k_scanC<<<nchunks, 1024, 0, stream>>>(tmp_scan, chunk_off, row_off, counts, N);
  k_fill<<<2048, 256, 0, stream>>>(dst, counts, csr, E);

  // ---- layer 1 ----
  k_gemm128<<<ceil_div(N, 16), 256, 0, stream>>>(x, W1, hA, N);
  k_node_dots<<<ceil_div(N, 4), 256, 0, stream>>>(hA, as1, ad1, al_s, al_d, N);
  k_agg<false><<<ceil_div(N, 4), 256, 0, stream>>>(row_off, csr, src, al_s, al_d,
      al_e1, loop_e, 0, hA, b1, oB, nullptr, nullptr, nullptr, nullptr, N);

  // ---- layer 2 (pooling fused into epilogue) ----
  k_gemm128<<<ceil_div(N, 16), 256, 0, stream>>>(oB, W2, hA, N);
  k_node_dots<<<ceil_div(N, 4), 256, 0, stream>>>(hA, as2, ad2, al_s, al_d, N);
  k_agg<true><<<ceil_div(N, 4), 256, 0, stream>>>(row_off, csr, src, al_s, al_d,
      al_e2, loop_e, 1, hA, b2, nullptr, Wfc, batchv, pool_sum, pool_cnt, N);

  // ---- finalize ----
  k_final<<<1, 256, 0, stream>>>(pool_sum, pool_cnt, bfc, out, G);
}

// Round 2
// 906.695 us; speedup vs baseline: 1.6643x; 1.6643x over previous
//
#include <hip/hip_runtime.h>
#include <hip/hip_bf16.h>
#include <cstdint>
#include <cstddef>

#define NEG_SLOPE 0.2f
#define HD 128   // hidden / feature dim
#define ED 50    // edge attr dim

static inline int ceil_div(int a, int b){ return (a + b - 1) / b; }

// ---------------- init: zero accumulators ----------------
__global__ void k_init(int* __restrict__ counts, float* __restrict__ pool_sum,
                       float* __restrict__ pool_cnt, float* __restrict__ al_e_sum,
                       int n, int g)
{
  int i = blockIdx.x * blockDim.x + threadIdx.x;
  int stride = gridDim.x * blockDim.x;
  for (int idx = i; idx < n; idx += stride) counts[idx] = 0;
  if (i < g) { pool_sum[i] = 0.f; pool_cnt[i] = 0.f; }
  if (i < 2) al_e_sum[i] = 0.f;
}

// ---------------- we_vec[l] = We_l @ ae_l (ED-vector) ----------------
__global__ void k_wevec(const float* __restrict__ We1, const float* __restrict__ ae1,
                        const float* __restrict__ We2, const float* __restrict__ ae2,
                        float* __restrict__ we_vec /*2*64*/)
{
  int l = blockIdx.x, d = threadIdx.x;
  const float* We = l ? We2 : We1;
  const float* ae = l ? ae2 : ae1;
  if (d < ED) {
    float s = 0.f;
    for (int k = 0; k < HD; ++k) s += We[d * HD + k] * ae[k];
    we_vec[l * 64 + d] = s;
  }
}

// ---------------- al_e[e] = edge_attr[e] . we_vec   (both layers, one pass) ----
// Stage 256 edges (pad-51 rows -> conflict-free) with coalesced float4 loads,
// then private per-thread dot products. NO LDS atomics.
__global__ __launch_bounds__(256) void k_edge_ale(
    const float* __restrict__ ea, const float* __restrict__ we_vec,
    float* __restrict__ al_e1, float* __restrict__ al_e2,
    float* __restrict__ al_e_sum, int E)
{
  __shared__ float sh[256 * 51];
  __shared__ float wv1[ED], wv2[ED];
  __shared__ float ws1[4], ws2[4];
  int tid = threadIdx.x;
  if (tid < ED) { wv1[tid] = we_vec[tid]; wv2[tid] = we_vec[64 + tid]; }

  int e0 = blockIdx.x * 256;
  int cnt = min(256, E - e0);
  int elems = (cnt > 0) ? cnt * ED : 0;
  const float* base = ea + (size_t)e0 * ED;
  const float4* base4 = (const float4*)base;   // e0*ED*4 bytes is 16B-aligned
  int n4 = elems >> 2;
  for (int i = tid; i < n4; i += 256) {
    float4 v = base4[i];
    int f = i << 2;
    int le = f / ED; int d = f - le * ED; sh[le * 51 + d] = v.x;
    f++; le = f / ED; d = f - le * ED;    sh[le * 51 + d] = v.y;
    f++; le = f / ED; d = f - le * ED;    sh[le * 51 + d] = v.z;
    f++; le = f / ED; d = f - le * ED;    sh[le * 51 + d] = v.w;
  }
  for (int i = (n4 << 2) + tid; i < elems; i += 256) {
    int le = i / ED, d = i - le * ED;
    sh[le * 51 + d] = base[i];
  }
  __syncthreads();

  float a1 = 0.f, a2 = 0.f;
  if (tid < cnt) {
    const float* row = &sh[tid * 51];
#pragma unroll
    for (int d = 0; d < ED; ++d) {
      float v = row[d];
      a1 = fmaf(v, wv1[d], a1);
      a2 = fmaf(v, wv2[d], a2);
    }
    al_e1[e0 + tid] = a1;
    al_e2[e0 + tid] = a2;
  }
  // block-level sum for the self-loop mean (one global atomic per block)
  float s1 = a1, s2 = a2;
#pragma unroll
  for (int o = 32; o; o >>= 1) { s1 += __shfl_xor(s1, o); s2 += __shfl_xor(s2, o); }
  int lane = tid & 63, wave = tid >> 6;
  if (lane == 0) { ws1[wave] = s1; ws2[wave] = s2; }
  __syncthreads();
  if (tid == 0) {
    atomicAdd(&al_e_sum[0], ws1[0] + ws1[1] + ws1[2] + ws1[3]);
    atomicAdd(&al_e_sum[1], ws2[0] + ws2[1] + ws2[2] + ws2[3]);
  }
}

// loop_e[l] = mean_e al_e[l][e]  (== mean(edge_attr) @ We @ ae)
__global__ void k_loop_e(const float* __restrict__ al_e_sum, float* __restrict__ loop_e, float invE)
{
  int t = threadIdx.x;
  if (t < 2) loop_e[t] = al_e_sum[t] * invE;
}

// ---------------- CSR build over dst ----------------
__global__ void k_count(const int* __restrict__ dst, int* __restrict__ counts, int E)
{
  int i = blockIdx.x * blockDim.x + threadIdx.x;
  int stride = gridDim.x * blockDim.x;
  for (; i < E; i += stride) atomicAdd(&counts[dst[i]], 1);
}

__global__ __launch_bounds__(1024) void k_scanA(const int* __restrict__ counts, int* __restrict__ tmp,
                                                int* __restrict__ chunk_sums, int n)
{
  __shared__ int sd[1024];
  int tid = threadIdx.x;
  int i = blockIdx.x * 1024 + tid;
  int v = (i < n) ? counts[i] : 0;
  sd[tid] = v;
  __syncthreads();
  for (int off = 1; off < 1024; off <<= 1) {
    int t = (tid >= off) ? sd[tid - off] : 0;
    __syncthreads();
    sd[tid] += t;
    __syncthreads();
  }
  if (i < n) tmp[i] = sd[tid] - v;   // exclusive
  if (tid == 1023) chunk_sums[blockIdx.x] = sd[1023];
}

__global__ void k_scanB(const int* __restrict__ chunk_sums, int* __restrict__ chunk_off,
                        int nchunks, int* __restrict__ row_off_end)
{
  if (threadIdx.x == 0) {
    int run = 0;
    for (int c = 0; c < nchunks; ++c) { chunk_off[c] = run; run += chunk_sums[c]; }
    *row_off_end = run;
  }
}

__global__ __launch_bounds__(1024) void k_scanC(const int* __restrict__ tmp, const int* __restrict__ chunk_off,
                                                int* __restrict__ row_off, int* __restrict__ cursor, int n)
{
  int i = blockIdx.x * 1024 + threadIdx.x;
  if (i < n) {
    int v = tmp[i] + chunk_off[blockIdx.x];
    row_off[i] = v;
    cursor[i] = v;
  }
}

__global__ void k_fill(const int* __restrict__ dst, int* __restrict__ cursor,
                       int* __restrict__ csr, int E)
{
  int i = blockIdx.x * blockDim.x + threadIdx.x;
  int stride = gridDim.x * blockDim.x;
  for (; i < E; i += stride) {
    int d = dst[i];
    int pos = atomicAdd(&cursor[d], 1);
    csr[pos] = i;
  }
}

// ---------------- C[M,128] = A[M,128] @ W[128,128] ----------------
// 32 rows/block, 4x4 register tile per thread, W staged in LDS, ds_read_b128.
__global__ __launch_bounds__(256) void k_gemm128(const float* __restrict__ A,
                                                 const float* __restrict__ W,
                                                 float* __restrict__ C, int M)
{
  __shared__ float Wl[HD * HD];
  int tid = threadIdx.x;
  {
    const float4* W4 = (const float4*)W;
    float4* Wl4 = (float4*)Wl;
#pragma unroll
    for (int i = 0; i < 16; ++i) Wl4[tid + i * 256] = W4[tid + i * 256];
  }
  __syncthreads();

  int q = tid & 31;        // column quad: cols 4q..4q+3
  int rg = tid >> 5;       // row group 0..7, 4 rows each -> 32 rows/block
  int row0 = blockIdx.x * 32 + rg * 4;

  const float* xr0 = A + (size_t)(row0 + 0 < M ? row0 + 0 : M - 1) * HD;
  const float* xr1 = A + (size_t)(row0 + 1 < M ? row0 + 1 : M - 1) * HD;
  const float* xr2 = A + (size_t)(row0 + 2 < M ? row0 + 2 : M - 1) * HD;
  const float* xr3 = A + (size_t)(row0 + 3 < M ? row0 + 3 : M - 1) * HD;

  float4 acc0 = {0.f,0.f,0.f,0.f}, acc1 = acc0, acc2 = acc0, acc3 = acc0;

  for (int k = 0; k < HD; k += 4) {
    const float* wk = &Wl[k * HD + 4 * q];
    float4 w0 = *(const float4*)(wk);
    float4 w1 = *(const float4*)(wk + HD);
    float4 w2 = *(const float4*)(wk + 2 * HD);
    float4 w3 = *(const float4*)(wk + 3 * HD);
    float4 xa = *(const float4*)(xr0 + k);
    float4 xb = *(const float4*)(xr1 + k);
    float4 xc = *(const float4*)(xr2 + k);
    float4 xd = *(const float4*)(xr3 + k);
#define ROWFMA(ACC, XV)                                                   \
    ACC.x = fmaf(XV.x, w0.x, ACC.x); ACC.x = fmaf(XV.y, w1.x, ACC.x);     \
    ACC.x = fmaf(XV.z, w2.x, ACC.x); ACC.x = fmaf(XV.w, w3.x, ACC.x);     \
    ACC.y = fmaf(XV.x, w0.y, ACC.y); ACC.y = fmaf(XV.y, w1.y, ACC.y);     \
    ACC.y = fmaf(XV.z, w2.y, ACC.y); ACC.y = fmaf(XV.w, w3.y, ACC.y);     \
    ACC.z = fmaf(XV.x, w0.z, ACC.z); ACC.z = fmaf(XV.y, w1.z, ACC.z);     \
    ACC.z = fmaf(XV.z, w2.z, ACC.z); ACC.z = fmaf(XV.w, w3.z, ACC.z);     \
    ACC.w = fmaf(XV.x, w0.w, ACC.w); ACC.w = fmaf(XV.y, w1.w, ACC.w);     \
    ACC.w = fmaf(XV.z, w2.w, ACC.w); ACC.w = fmaf(XV.w, w3.w, ACC.w);
    ROWFMA(acc0, xa)
    ROWFMA(acc1, xb)
    ROWFMA(acc2, xc)
    ROWFMA(acc3, xd)
#undef ROWFMA
  }

  if (row0 + 0 < M) *(float4*)&C[(size_t)(row0 + 0) * HD + 4 * q] = acc0;
  if (row0 + 1 < M) *(float4*)&C[(size_t)(row0 + 1) * HD + 4 * q] = acc1;
  if (row0 + 2 < M) *(float4*)&C[(size_t)(row0 + 2) * HD + 4 * q] = acc2;
  if (row0 + 3 < M) *(float4*)&C[(size_t)(row0 + 3) * HD + 4 * q] = acc3;
}

// ---------------- al_s[n] = h[n].as, al_d[n] = h[n].ad ----------------
__global__ void k_node_dots(const float* __restrict__ h, const float* __restrict__ a_s,
                            const float* __restrict__ a_d, float* __restrict__ al_s,
                            float* __restrict__ al_d, int n)
{
  int wave = threadIdx.x >> 6, lane = threadIdx.x & 63;
  int node = blockIdx.x * 4 + wave;
  if (node >= n) return;
  const float* hr = h + (size_t)node * HD;
  float v1 = hr[lane], v2 = hr[lane + 64];
  float ss = v1 * a_s[lane] + v2 * a_s[lane + 64];
  float dd = v1 * a_d[lane] + v2 * a_d[lane + 64];
#pragma unroll
  for (int o = 32; o; o >>= 1) { ss += __shfl_xor(ss, o); dd += __shfl_xor(dd, o); }
  if (lane == 0) { al_s[node] = ss; al_d[node] = dd; }
}

// ---------------- GAT aggregation: one wave per dst node ----------------
template <bool FUSE>
__global__ __launch_bounds__(256) void k_agg(
    const int* __restrict__ row_off, const int* __restrict__ csr,
    const int* __restrict__ src,
    const float* __restrict__ al_s, const float* __restrict__ al_d,
    const float* __restrict__ al_e, const float* __restrict__ loop_e, int le_idx,
    const float* __restrict__ h, const float* __restrict__ bias,
    float* __restrict__ o,
    const float* __restrict__ Wfc, const int* __restrict__ batchv,
    float* __restrict__ pool_sum, float* __restrict__ pool_cnt,
    int n_nodes)
{
  int wave = threadIdx.x >> 6, lane = threadIdx.x & 63;
  int n = blockIdx.x * 4 + wave;
  if (n >= n_nodes) return;

  float led  = loop_e[le_idx];
  float ad_n = al_d[n];

  // self loop (src = dst = n); alphas are O(1): exp without max-shift is exact enough
  float a0 = al_s[n] + ad_n + led;
  a0 = a0 > 0.f ? a0 : NEG_SLOPE * a0;
  float w = __expf(a0);
  const float* hn = h + (size_t)n * HD;
  float acc1 = w * hn[lane];
  float acc2 = w * hn[lane + 64];
  float s = w;

  int k0 = row_off[n], k1 = row_off[n + 1];
  for (int k = k0; k < k1; ++k) {
    int e  = csr[k];
    int sn = src[e];
    float a = al_s[sn] + ad_n + al_e[e];
    a = a > 0.f ? a : NEG_SLOPE * a;
    float we = __expf(a);
    s += we;
    const float* hs = h + (size_t)sn * HD;
    acc1 += we * hs[lane];
    acc2 += we * hs[lane + 64];
  }

  float inv = 1.0f / s;
  float o1v = fmaxf(acc1 * inv + bias[lane], 0.f);
  float o2v = fmaxf(acc2 * inv + bias[lane + 64], 0.f);

  if (FUSE) {
    float t = o1v * Wfc[lane] + o2v * Wfc[lane + 64];
#pragma unroll
    for (int ofs = 32; ofs; ofs >>= 1) t += __shfl_xor(t, ofs);
    if (lane == 0) {
      int g = batchv[n];
      atomicAdd(&pool_sum[g], t);
      atomicAdd(&pool_cnt[g], 1.0f);
    }
  } else {
    float* orow = o + (size_t)n * HD;
    orow[lane] = o1v;
    orow[lane + 64] = o2v;
  }
}

// ---------------- finalize ----------------
__global__ void k_final(const float* __restrict__ pool_sum, const float* __restrict__ pool_cnt,
                        const float* __restrict__ bfc, float* __restrict__ out, int g)
{
  int i = blockIdx.x * blockDim.x + threadIdx.x;
  if (i < g) out[i] = pool_sum[i] / fmaxf(pool_cnt[i], 1.f) + bfc[0];
}

// =====================================================================
extern "C" void kernel_launch(void* const* d_in, const int* in_sizes, int n_in,
                              void* d_out, int out_size, void* d_ws, size_t ws_size,
                              hipStream_t stream)
{
  const float* x       = (const float*)d_in[0];
  const int*   ei      = (const int*)d_in[1];
  const float* ea      = (const float*)d_in[2];
  const int*   batchv  = (const int*)d_in[3];
  const float* W1  = (const float*)d_in[4];
  const float* as1 = (const float*)d_in[5];
  const float* ad1 = (const float*)d_in[6];
  const float* We1 = (const float*)d_in[7];
  const float* ae1 = (const float*)d_in[8];
  const float* b1  = (const float*)d_in[9];
  const float* W2  = (const float*)d_in[10];
  const float* as2 = (const float*)d_in[11];
  const float* ad2 = (const float*)d_in[12];
  const float* We2 = (const float*)d_in[13];
  const float* ae2 = (const float*)d_in[14];
  const float* b2  = (const float*)d_in[15];
  const float* Wfc = (const float*)d_in[16];
  const float* bfc = (const float*)d_in[17];
  float* out = (float*)d_out;

  const int N = in_sizes[0] / HD;
  const int E = in_sizes[1] / 2;
  const int G = out_size;               // 256 graphs, OUT=1
  const int* src = ei;
  const int* dst = ei + E;

  // ---- carve workspace ----
  char* p = (char*)d_ws;
  auto alloc = [&](size_t bytes) -> void* {
    void* r = (void*)p;
    p += (bytes + 255) & ~(size_t)255;
    return r;
  };
  float* hA       = (float*)alloc((size_t)N * HD * 4);   // h1, then h2
  float* oB       = (float*)alloc((size_t)N * HD * 4);   // relu(gat1)
  float* al_e1    = (float*)alloc((size_t)E * 4);
  float* al_e2    = (float*)alloc((size_t)E * 4);
  float* al_s     = (float*)alloc((size_t)N * 4);
  float* al_d     = (float*)alloc((size_t)N * 4);
  int*   counts   = (int*)alloc((size_t)N * 4);          // then reused as cursor
  int*   row_off  = (int*)alloc((size_t)(N + 1) * 4);
  int*   tmp_scan = (int*)alloc((size_t)N * 4);
  int*   chunk_sums = (int*)alloc(64 * 4);
  int*   chunk_off  = (int*)alloc(64 * 4);
  int*   csr      = (int*)alloc((size_t)E * 4);
  float* we_vec   = (float*)alloc(2 * 64 * 4);
  float* al_e_sum = (float*)alloc(2 * 4);
  float* loop_e   = (float*)alloc(2 * 4);
  float* pool_sum = (float*)alloc((size_t)G * 4);
  float* pool_cnt = (float*)alloc((size_t)G * 4);
  (void)ws_size; (void)n_in;

  const int nchunks = ceil_div(N, 1024);

  k_init<<<ceil_div(N, 256), 256, 0, stream>>>(counts, pool_sum, pool_cnt, al_e_sum, N, G);
  k_wevec<<<2, 64, 0, stream>>>(We1, ae1, We2, ae2, we_vec);
  k_edge_ale<<<ceil_div(E, 256), 256, 0, stream>>>(ea, we_vec, al_e1, al_e2, al_e_sum, E);
  k_loop_e<<<1, 64, 0, stream>>>(al_e_sum, loop_e, 1.0f / (float)E);
  k_count<<<2048, 256, 0, stream>>>(dst, counts, E);
  k_scanA<<<nchunks, 1024, 0, stream>>>(counts, tmp_scan, chunk_sums, N);
  k_scanB<<<1, 64, 0, stream>>>(chunk_sums, chunk_off, nchunks, &row_off[N]);
  k_scanC<<<nchunks, 1024, 0, stream>>>(tmp_scan, chunk_off, row_off, counts, N);
  k_fill<<<2048, 256, 0, stream>>>(dst, counts, csr, E);

  // ---- layer 1 ----
  k_gemm128<<<ceil_div(N, 32), 256, 0, stream>>>(x, W1, hA, N);
  k_node_dots<<<ceil_div(N, 4), 256, 0, stream>>>(hA, as1, ad1, al_s, al_d, N);
  k_agg<false><<<ceil_div(N, 4), 256, 0, stream>>>(row_off, csr, src, al_s, al_d,
      al_e1, loop_e, 0, hA, b1, oB, nullptr, nullptr, nullptr, nullptr, N);

  // ---- layer 2 (pooling fused into epilogue) ----
  k_gemm128<<<ceil_div(N, 32), 256, 0, stream>>>(oB, W2, hA, N);
  k_node_dots<<<ceil_div(N, 4), 256, 0, stream>>>(hA, as2, ad2, al_s, al_d, N);
  k_agg<true><<<ceil_div(N, 4), 256, 0, stream>>>(row_off, csr, src, al_s, al_d,
      al_e2, loop_e, 1, hA, b2, nullptr, Wfc, batchv, pool_sum, pool_cnt, N);

  k_final<<<1, 256, 0, stream>>>(pool_sum, pool_cnt, bfc, out, G);
}

// Round 3
// 872.780 us; speedup vs baseline: 1.7290x; 1.0389x over previous
//
#include <hip/hip_runtime.h>
#include <hip/hip_bf16.h>
#include <cstdint>
#include <cstddef>

#define NEG_SLOPE 0.2f
#define HD 128   // hidden / feature dim
#define ED 50    // edge attr dim

static inline int ceil_div(int a, int b){ return (a + b - 1) / b; }

// ---------------- init: zero accumulators ----------------
__global__ void k_init(int* __restrict__ counts, float* __restrict__ pool_sum,
                       float* __restrict__ pool_cnt, float* __restrict__ al_e_sum,
                       int n, int g)
{
  int i = blockIdx.x * blockDim.x + threadIdx.x;
  int stride = gridDim.x * blockDim.x;
  for (int idx = i; idx < n; idx += stride) counts[idx] = 0;
  if (i < g) { pool_sum[i] = 0.f; pool_cnt[i] = 0.f; }
  if (i < 2) al_e_sum[i] = 0.f;
}

// ---------------- we_vec[l] = We_l @ ae_l (ED-vector) ----------------
__global__ void k_wevec(const float* __restrict__ We1, const float* __restrict__ ae1,
                        const float* __restrict__ We2, const float* __restrict__ ae2,
                        float* __restrict__ we_vec /*2*64*/)
{
  int l = blockIdx.x, d = threadIdx.x;
  const float* We = l ? We2 : We1;
  const float* ae = l ? ae2 : ae1;
  if (d < ED) {
    float s = 0.f;
    for (int k = 0; k < HD; ++k) s += We[d * HD + k] * ae[k];
    we_vec[l * 64 + d] = s;
  }
}

// ---------------- al_e[e] = edge_attr[e] . we_vec (both layers, one pass) ----
__global__ __launch_bounds__(256) void k_edge_ale(
    const float* __restrict__ ea, const float* __restrict__ we_vec,
    float* __restrict__ al_e1, float* __restrict__ al_e2,
    float* __restrict__ al_e_sum, int E)
{
  __shared__ float sh[256 * 51];
  __shared__ float wv1[ED], wv2[ED];
  __shared__ float ws1[4], ws2[4];
  int tid = threadIdx.x;
  if (tid < ED) { wv1[tid] = we_vec[tid]; wv2[tid] = we_vec[64 + tid]; }

  int e0 = blockIdx.x * 256;
  int cnt = min(256, E - e0);
  int elems = (cnt > 0) ? cnt * ED : 0;
  const float* base = ea + (size_t)e0 * ED;
  const float4* base4 = (const float4*)base;
  int n4 = elems >> 2;
  for (int i = tid; i < n4; i += 256) {
    float4 v = base4[i];
    int f = i << 2;
    int le = f / ED; int d = f - le * ED; sh[le * 51 + d] = v.x;
    f++; le = f / ED; d = f - le * ED;    sh[le * 51 + d] = v.y;
    f++; le = f / ED; d = f - le * ED;    sh[le * 51 + d] = v.z;
    f++; le = f / ED; d = f - le * ED;    sh[le * 51 + d] = v.w;
  }
  for (int i = (n4 << 2) + tid; i < elems; i += 256) {
    int le = i / ED, d = i - le * ED;
    sh[le * 51 + d] = base[i];
  }
  __syncthreads();

  float a1 = 0.f, a2 = 0.f;
  if (tid < cnt) {
    const float* row = &sh[tid * 51];
#pragma unroll
    for (int d = 0; d < ED; ++d) {
      float v = row[d];
      a1 = fmaf(v, wv1[d], a1);
      a2 = fmaf(v, wv2[d], a2);
    }
    al_e1[e0 + tid] = a1;
    al_e2[e0 + tid] = a2;
  }
  float s1 = a1, s2 = a2;
#pragma unroll
  for (int o = 32; o; o >>= 1) { s1 += __shfl_xor(s1, o); s2 += __shfl_xor(s2, o); }
  int lane = tid & 63, wave = tid >> 6;
  if (lane == 0) { ws1[wave] = s1; ws2[wave] = s2; }
  __syncthreads();
  if (tid == 0) {
    atomicAdd(&al_e_sum[0], ws1[0] + ws1[1] + ws1[2] + ws1[3]);
    atomicAdd(&al_e_sum[1], ws2[0] + ws2[1] + ws2[2] + ws2[3]);
  }
}

__global__ void k_loop_e(const float* __restrict__ al_e_sum, float* __restrict__ loop_e, float invE)
{
  int t = threadIdx.x;
  if (t < 2) loop_e[t] = al_e_sum[t] * invE;
}

// ---------------- CSR build over dst ----------------
__global__ void k_count(const int* __restrict__ dst, int* __restrict__ counts, int E)
{
  int i = blockIdx.x * blockDim.x + threadIdx.x;
  int stride = gridDim.x * blockDim.x;
  for (; i < E; i += stride) atomicAdd(&counts[dst[i]], 1);
}

__global__ __launch_bounds__(1024) void k_scanA(const int* __restrict__ counts, int* __restrict__ tmp,
                                                int* __restrict__ chunk_sums, int n)
{
  __shared__ int sd[1024];
  int tid = threadIdx.x;
  int i = blockIdx.x * 1024 + tid;
  int v = (i < n) ? counts[i] : 0;
  sd[tid] = v;
  __syncthreads();
  for (int off = 1; off < 1024; off <<= 1) {
    int t = (tid >= off) ? sd[tid - off] : 0;
    __syncthreads();
    sd[tid] += t;
    __syncthreads();
  }
  if (i < n) tmp[i] = sd[tid] - v;   // exclusive
  if (tid == 1023) chunk_sums[blockIdx.x] = sd[1023];
}

__global__ void k_scanB(const int* __restrict__ chunk_sums, int* __restrict__ chunk_off,
                        int nchunks, int* __restrict__ row_off_end)
{
  if (threadIdx.x == 0) {
    int run = 0;
    for (int c = 0; c < nchunks; ++c) { chunk_off[c] = run; run += chunk_sums[c]; }
    *row_off_end = run;
  }
}

__global__ __launch_bounds__(1024) void k_scanC(const int* __restrict__ tmp, const int* __restrict__ chunk_off,
                                                int* __restrict__ row_off, int* __restrict__ cursor, int n)
{
  int i = blockIdx.x * 1024 + threadIdx.x;
  if (i < n) {
    int v = tmp[i] + chunk_off[blockIdx.x];
    row_off[i] = v;
    cursor[i] = v;
  }
}

// scatter CSR payload: edata[pos] = {src, dst, al_e1, al_e2}  (one 16B store)
__global__ void k_fill(const int* __restrict__ src, const int* __restrict__ dst,
                       const float* __restrict__ al_e1, const float* __restrict__ al_e2,
                       int* __restrict__ cursor, float4* __restrict__ edata, int E)
{
  int i = blockIdx.x * blockDim.x + threadIdx.x;
  int stride = gridDim.x * blockDim.x;
  for (; i < E; i += stride) {
    int d = dst[i];
    int pos = atomicAdd(&cursor[d], 1);
    float4 v;
    v.x = __int_as_float(src[i]);
    v.y = __int_as_float(d);
    v.z = al_e1[i];
    v.w = al_e2[i];
    edata[pos] = v;
  }
}

// ---------------- C[M,128] = A[M,128] @ W[128,128]  + fused al_s/al_d dots ----
// 32 rows/block, 4x4 register tile per thread, W staged in LDS.
__global__ __launch_bounds__(256) void k_gemm128(const float* __restrict__ A,
                                                 const float* __restrict__ W,
                                                 float* __restrict__ C,
                                                 const float* __restrict__ a_s,
                                                 const float* __restrict__ a_d,
                                                 float* __restrict__ al_s,
                                                 float* __restrict__ al_d,
                                                 int M)
{
  __shared__ float Wl[HD * HD];
  int tid = threadIdx.x;
  {
    const float4* W4 = (const float4*)W;
    float4* Wl4 = (float4*)Wl;
#pragma unroll
    for (int i = 0; i < 16; ++i) Wl4[tid + i * 256] = W4[tid + i * 256];
  }
  __syncthreads();

  int q = tid & 31;        // column quad: cols 4q..4q+3
  int rg = tid >> 5;       // row group 0..7, 4 rows each -> 32 rows/block
  int row0 = blockIdx.x * 32 + rg * 4;

  const float* xr0 = A + (size_t)(row0 + 0 < M ? row0 + 0 : M - 1) * HD;
  const float* xr1 = A + (size_t)(row0 + 1 < M ? row0 + 1 : M - 1) * HD;
  const float* xr2 = A + (size_t)(row0 + 2 < M ? row0 + 2 : M - 1) * HD;
  const float* xr3 = A + (size_t)(row0 + 3 < M ? row0 + 3 : M - 1) * HD;

  float4 acc0 = {0.f,0.f,0.f,0.f}, acc1 = acc0, acc2 = acc0, acc3 = acc0;

  for (int k = 0; k < HD; k += 4) {
    const float* wk = &Wl[k * HD + 4 * q];
    float4 w0 = *(const float4*)(wk);
    float4 w1 = *(const float4*)(wk + HD);
    float4 w2 = *(const float4*)(wk + 2 * HD);
    float4 w3 = *(const float4*)(wk + 3 * HD);
    float4 xa = *(const float4*)(xr0 + k);
    float4 xb = *(const float4*)(xr1 + k);
    float4 xc = *(const float4*)(xr2 + k);
    float4 xd = *(const float4*)(xr3 + k);
#define ROWFMA(ACC, XV)                                                   \
    ACC.x = fmaf(XV.x, w0.x, ACC.x); ACC.x = fmaf(XV.y, w1.x, ACC.x);     \
    ACC.x = fmaf(XV.z, w2.x, ACC.x); ACC.x = fmaf(XV.w, w3.x, ACC.x);     \
    ACC.y = fmaf(XV.x, w0.y, ACC.y); ACC.y = fmaf(XV.y, w1.y, ACC.y);     \
    ACC.y = fmaf(XV.z, w2.y, ACC.y); ACC.y = fmaf(XV.w, w3.y, ACC.y);     \
    ACC.z = fmaf(XV.x, w0.z, ACC.z); ACC.z = fmaf(XV.y, w1.z, ACC.z);     \
    ACC.z = fmaf(XV.z, w2.z, ACC.z); ACC.z = fmaf(XV.w, w3.z, ACC.z);     \
    ACC.w = fmaf(XV.x, w0.w, ACC.w); ACC.w = fmaf(XV.y, w1.w, ACC.w);     \
    ACC.w = fmaf(XV.z, w2.w, ACC.w); ACC.w = fmaf(XV.w, w3.w, ACC.w);
    ROWFMA(acc0, xa)
    ROWFMA(acc1, xb)
    ROWFMA(acc2, xc)
    ROWFMA(acc3, xd)
#undef ROWFMA
  }

  if (row0 + 0 < M) *(float4*)&C[(size_t)(row0 + 0) * HD + 4 * q] = acc0;
  if (row0 + 1 < M) *(float4*)&C[(size_t)(row0 + 1) * HD + 4 * q] = acc1;
  if (row0 + 2 < M) *(float4*)&C[(size_t)(row0 + 2) * HD + 4 * q] = acc2;
  if (row0 + 3 < M) *(float4*)&C[(size_t)(row0 + 3) * HD + 4 * q] = acc3;

  // fused node dots: al_s[row] = C[row,:].a_s ; al_d likewise (reduce over 32 col-lanes)
  float4 asv = *(const float4*)&a_s[4 * q];
  float4 adv = *(const float4*)&a_d[4 * q];
  float ps0 = acc0.x*asv.x + acc0.y*asv.y + acc0.z*asv.z + acc0.w*asv.w;
  float ps1 = acc1.x*asv.x + acc1.y*asv.y + acc1.z*asv.z + acc1.w*asv.w;
  float ps2 = acc2.x*asv.x + acc2.y*asv.y + acc2.z*asv.z + acc2.w*asv.w;
  float ps3 = acc3.x*asv.x + acc3.y*asv.y + acc3.z*asv.z + acc3.w*asv.w;
  float pd0 = acc0.x*adv.x + acc0.y*adv.y + acc0.z*adv.z + acc0.w*adv.w;
  float pd1 = acc1.x*adv.x + acc1.y*adv.y + acc1.z*adv.z + acc1.w*adv.w;
  float pd2 = acc2.x*adv.x + acc2.y*adv.y + acc2.z*adv.z + acc2.w*adv.w;
  float pd3 = acc3.x*adv.x + acc3.y*adv.y + acc3.z*adv.z + acc3.w*adv.w;
#pragma unroll
  for (int o = 16; o; o >>= 1) {
    ps0 += __shfl_xor(ps0, o); ps1 += __shfl_xor(ps1, o);
    ps2 += __shfl_xor(ps2, o); ps3 += __shfl_xor(ps3, o);
    pd0 += __shfl_xor(pd0, o); pd1 += __shfl_xor(pd1, o);
    pd2 += __shfl_xor(pd2, o); pd3 += __shfl_xor(pd3, o);
  }
  if (q == 0) {
    if (row0 + 0 < M) { al_s[row0 + 0] = ps0; al_d[row0 + 0] = pd0; }
    if (row0 + 1 < M) { al_s[row0 + 1] = ps1; al_d[row0 + 1] = pd1; }
    if (row0 + 2 < M) { al_s[row0 + 2] = ps2; al_d[row0 + 2] = pd2; }
    if (row0 + 3 < M) { al_s[row0 + 3] = ps3; al_d[row0 + 3] = pd3; }
  }
}

// ---------------- per-edge attention weight (CSR order, coalesced) ----------
__global__ __launch_bounds__(256) void k_edge_w(
    const float4* __restrict__ edata, const float* __restrict__ al_s,
    const float* __restrict__ al_d, float2* __restrict__ pack, int E, int layer)
{
  int k = blockIdx.x * 256 + threadIdx.x;
  if (k >= E) return;
  float4 v = edata[k];
  int sn = __float_as_int(v.x);
  int dn = __float_as_int(v.y);
  float ale = layer ? v.w : v.z;
  float a = al_s[sn] + al_d[dn] + ale;
  a = a > 0.f ? a : NEG_SLOPE * a;
  pack[k] = make_float2(v.x, __expf(a));
}

// ---------------- GAT aggregation: one wave per dst node, unrolled gathers ----
template <bool FUSE>
__global__ __launch_bounds__(256) void k_agg(
    const int* __restrict__ row_off, const float2* __restrict__ pack,
    const float* __restrict__ al_s, const float* __restrict__ al_d,
    const float* __restrict__ loop_e, int le_idx,
    const float* __restrict__ h, const float* __restrict__ bias,
    float* __restrict__ o,
    const float* __restrict__ Wfc, const int* __restrict__ batchv,
    float* __restrict__ pool_sum, float* __restrict__ pool_cnt,
    int n_nodes)
{
  int wave = threadIdx.x >> 6, lane = threadIdx.x & 63;
  int n = blockIdx.x * 4 + wave;
  if (n >= n_nodes) return;

  // self loop; alphas are O(1): exp without max-shift is safe
  float a0 = al_s[n] + al_d[n] + loop_e[le_idx];
  a0 = a0 > 0.f ? a0 : NEG_SLOPE * a0;
  float w = __expf(a0);
  const float* hn = h + (size_t)n * HD;
  float acc1 = w * hn[lane];
  float acc2 = w * hn[lane + 64];
  float s = w;

  int k0 = row_off[n];
  int cnt = row_off[n + 1] - k0;
  const float2* pk = pack + k0;
  int k = 0;
  for (; k + 4 <= cnt; k += 4) {
    float2 p0 = pk[k], p1 = pk[k + 1], p2 = pk[k + 2], p3 = pk[k + 3];
    const float* h0 = h + (size_t)__float_as_int(p0.x) * HD;
    const float* h1 = h + (size_t)__float_as_int(p1.x) * HD;
    const float* h2 = h + (size_t)__float_as_int(p2.x) * HD;
    const float* h3 = h + (size_t)__float_as_int(p3.x) * HD;
    float v0a = h0[lane], v0b = h0[lane + 64];
    float v1a = h1[lane], v1b = h1[lane + 64];
    float v2a = h2[lane], v2b = h2[lane + 64];
    float v3a = h3[lane], v3b = h3[lane + 64];
    s += p0.y + p1.y + p2.y + p3.y;
    acc1 = fmaf(p0.y, v0a, acc1); acc2 = fmaf(p0.y, v0b, acc2);
    acc1 = fmaf(p1.y, v1a, acc1); acc2 = fmaf(p1.y, v1b, acc2);
    acc1 = fmaf(p2.y, v2a, acc1); acc2 = fmaf(p2.y, v2b, acc2);
    acc1 = fmaf(p3.y, v3a, acc1); acc2 = fmaf(p3.y, v3b, acc2);
  }
  for (; k < cnt; ++k) {
    float2 p = pk[k];
    const float* hs = h + (size_t)__float_as_int(p.x) * HD;
    s += p.y;
    acc1 = fmaf(p.y, hs[lane], acc1);
    acc2 = fmaf(p.y, hs[lane + 64], acc2);
  }

  float inv = 1.0f / s;
  float o1v = fmaxf(acc1 * inv + bias[lane], 0.f);
  float o2v = fmaxf(acc2 * inv + bias[lane + 64], 0.f);

  if (FUSE) {
    float t = o1v * Wfc[lane] + o2v * Wfc[lane + 64];
#pragma unroll
    for (int ofs = 32; ofs; ofs >>= 1) t += __shfl_xor(t, ofs);
    if (lane == 0) {
      int g = batchv[n];
      atomicAdd(&pool_sum[g], t);
      atomicAdd(&pool_cnt[g], 1.0f);
    }
  } else {
    float* orow = o + (size_t)n * HD;
    orow[lane] = o1v;
    orow[lane + 64] = o2v;
  }
}

// ---------------- finalize ----------------
__global__ void k_final(const float* __restrict__ pool_sum, const float* __restrict__ pool_cnt,
                        const float* __restrict__ bfc, float* __restrict__ out, int g)
{
  int i = blockIdx.x * blockDim.x + threadIdx.x;
  if (i < g) out[i] = pool_sum[i] / fmaxf(pool_cnt[i], 1.f) + bfc[0];
}

// =====================================================================
extern "C" void kernel_launch(void* const* d_in, const int* in_sizes, int n_in,
                              void* d_out, int out_size, void* d_ws, size_t ws_size,
                              hipStream_t stream)
{
  const float* x       = (const float*)d_in[0];
  const int*   ei      = (const int*)d_in[1];
  const float* ea      = (const float*)d_in[2];
  const int*   batchv  = (const int*)d_in[3];
  const float* W1  = (const float*)d_in[4];
  const float* as1 = (const float*)d_in[5];
  const float* ad1 = (const float*)d_in[6];
  const float* We1 = (const float*)d_in[7];
  const float* ae1 = (const float*)d_in[8];
  const float* b1  = (const float*)d_in[9];
  const float* W2  = (const float*)d_in[10];
  const float* as2 = (const float*)d_in[11];
  const float* ad2 = (const float*)d_in[12];
  const float* We2 = (const float*)d_in[13];
  const float* ae2 = (const float*)d_in[14];
  const float* b2  = (const float*)d_in[15];
  const float* Wfc = (const float*)d_in[16];
  const float* bfc = (const float*)d_in[17];
  float* out = (float*)d_out;

  const int N = in_sizes[0] / HD;
  const int E = in_sizes[1] / 2;
  const int G = out_size;               // 256 graphs, OUT=1
  const int* src = ei;
  const int* dst = ei + E;

  // ---- carve workspace ----
  char* p = (char*)d_ws;
  auto alloc = [&](size_t bytes) -> void* {
    void* r = (void*)p;
    p += (bytes + 255) & ~(size_t)255;
    return r;
  };
  float*  hA       = (float*)alloc((size_t)N * HD * 4);   // h1, then h2
  float*  oB       = (float*)alloc((size_t)N * HD * 4);   // relu(gat1)
  float*  al_e1    = (float*)alloc((size_t)E * 4);
  float*  al_e2    = (float*)alloc((size_t)E * 4);
  float*  al_s     = (float*)alloc((size_t)N * 4);
  float*  al_d     = (float*)alloc((size_t)N * 4);
  int*    counts   = (int*)alloc((size_t)N * 4);          // then reused as cursor
  int*    row_off  = (int*)alloc((size_t)(N + 1) * 4);
  int*    tmp_scan = (int*)alloc((size_t)N * 4);
  int*    chunk_sums = (int*)alloc(64 * 4);
  int*    chunk_off  = (int*)alloc(64 * 4);
  float4* edata    = (float4*)alloc((size_t)E * 16);      // CSR payload {src,dst,ale1,ale2}
  float2* pack     = (float2*)alloc((size_t)E * 8);       // per-layer {src, w}
  float*  we_vec   = (float*)alloc(2 * 64 * 4);
  float*  al_e_sum = (float*)alloc(2 * 4);
  float*  loop_e   = (float*)alloc(2 * 4);
  float*  pool_sum = (float*)alloc((size_t)G * 4);
  float*  pool_cnt = (float*)alloc((size_t)G * 4);
  (void)ws_size; (void)n_in;

  const int nchunks = ceil_div(N, 1024);

  k_init<<<ceil_div(N, 256), 256, 0, stream>>>(counts, pool_sum, pool_cnt, al_e_sum, N, G);
  k_wevec<<<2, 64, 0, stream>>>(We1, ae1, We2, ae2, we_vec);
  k_edge_ale<<<ceil_div(E, 256), 256, 0, stream>>>(ea, we_vec, al_e1, al_e2, al_e_sum, E);
  k_loop_e<<<1, 64, 0, stream>>>(al_e_sum, loop_e, 1.0f / (float)E);
  k_count<<<2048, 256, 0, stream>>>(dst, counts, E);
  k_scanA<<<nchunks, 1024, 0, stream>>>(counts, tmp_scan, chunk_sums, N);
  k_scanB<<<1, 64, 0, stream>>>(chunk_sums, chunk_off, nchunks, &row_off[N]);
  k_scanC<<<nchunks, 1024, 0, stream>>>(tmp_scan, chunk_off, row_off, counts, N);
  k_fill<<<2048, 256, 0, stream>>>(src, dst, al_e1, al_e2, counts, edata, E);

  // ---- layer 1 ----
  k_gemm128<<<ceil_div(N, 32), 256, 0, stream>>>(x, W1, hA, as1, ad1, al_s, al_d, N);
  k_edge_w<<<ceil_div(E, 256), 256, 0, stream>>>(edata, al_s, al_d, pack, E, 0);
  k_agg<false><<<ceil_div(N, 4), 256, 0, stream>>>(row_off, pack, al_s, al_d,
      loop_e, 0, hA, b1, oB, nullptr, nullptr, nullptr, nullptr, N);

  // ---- layer 2 (pooling fused into epilogue) ----
  k_gemm128<<<ceil_div(N, 32), 256, 0, stream>>>(oB, W2, hA, as2, ad2, al_s, al_d, N);
  k_edge_w<<<ceil_div(E, 256), 256, 0, stream>>>(edata, al_s, al_d, pack, E, 1);
  k_agg<true><<<ceil_div(N, 4), 256, 0, stream>>>(row_off, pack, al_s, al_d,
      loop_e, 1, hA, b2, nullptr, Wfc, batchv, pool_sum, pool_cnt, N);

  k_final<<<1, 256, 0, stream>>>(pool_sum, pool_cnt, bfc, out, G);
}

// Round 4
// 756.966 us; speedup vs baseline: 1.9935x; 1.1530x over previous
//
#include <hip/hip_runtime.h>
#include <hip/hip_bf16.h>
#include <hip/hip_fp16.h>
#include <cstdint>
#include <cstddef>

#define NEG_SLOPE 0.2f
#define HD 128   // hidden / feature dim
#define ED 50    // edge attr dim

static inline int ceil_div(int a, int b){ return (a + b - 1) / b; }

union H2U { __half2 h; unsigned int u; };
__device__ inline unsigned int pack_h2(float a, float b) {
  H2U c; c.h = __floats2half2_rn(a, b); return c.u;
}
__device__ inline float2 unpack_h2(unsigned int v) {
  H2U c; c.u = v; return __half22float2(c.h);
}

// ---------------- init: zero accumulators ----------------
__global__ void k_init(int* __restrict__ counts, float* __restrict__ pool_sum,
                       float* __restrict__ pool_cnt, float* __restrict__ al_e_sum,
                       int n, int g)
{
  int i = blockIdx.x * blockDim.x + threadIdx.x;
  int stride = gridDim.x * blockDim.x;
  for (int idx = i; idx < n; idx += stride) counts[idx] = 0;
  if (i < g) { pool_sum[i] = 0.f; pool_cnt[i] = 0.f; }
  if (i < 2) al_e_sum[i] = 0.f;
}

// ---------------- we_vec[l] = We_l @ ae_l (ED-vector) ----------------
__global__ void k_wevec(const float* __restrict__ We1, const float* __restrict__ ae1,
                        const float* __restrict__ We2, const float* __restrict__ ae2,
                        float* __restrict__ we_vec /*2*64*/)
{
  int l = blockIdx.x, d = threadIdx.x;
  const float* We = l ? We2 : We1;
  const float* ae = l ? ae2 : ae1;
  if (d < ED) {
    float s = 0.f;
    for (int k = 0; k < HD; ++k) s += We[d * HD + k] * ae[k];
    we_vec[l * 64 + d] = s;
  }
}

// ---------------- al_e[e] = edge_attr[e] . we_vec (both layers, one pass) ----
__global__ __launch_bounds__(256) void k_edge_ale(
    const float* __restrict__ ea, const float* __restrict__ we_vec,
    float* __restrict__ al_e1, float* __restrict__ al_e2,
    float* __restrict__ al_e_sum, int E)
{
  __shared__ float sh[256 * 51];
  __shared__ float wv1[ED], wv2[ED];
  __shared__ float ws1[4], ws2[4];
  int tid = threadIdx.x;
  if (tid < ED) { wv1[tid] = we_vec[tid]; wv2[tid] = we_vec[64 + tid]; }

  int e0 = blockIdx.x * 256;
  int cnt = min(256, E - e0);
  int elems = (cnt > 0) ? cnt * ED : 0;
  const float* base = ea + (size_t)e0 * ED;
  const float4* base4 = (const float4*)base;
  int n4 = elems >> 2;
  for (int i = tid; i < n4; i += 256) {
    float4 v = base4[i];
    int f = i << 2;
    int le = f / ED; int d = f - le * ED; sh[le * 51 + d] = v.x;
    f++; le = f / ED; d = f - le * ED;    sh[le * 51 + d] = v.y;
    f++; le = f / ED; d = f - le * ED;    sh[le * 51 + d] = v.z;
    f++; le = f / ED; d = f - le * ED;    sh[le * 51 + d] = v.w;
  }
  for (int i = (n4 << 2) + tid; i < elems; i += 256) {
    int le = i / ED, d = i - le * ED;
    sh[le * 51 + d] = base[i];
  }
  __syncthreads();

  float a1 = 0.f, a2 = 0.f;
  if (tid < cnt) {
    const float* row = &sh[tid * 51];
#pragma unroll
    for (int d = 0; d < ED; ++d) {
      float v = row[d];
      a1 = fmaf(v, wv1[d], a1);
      a2 = fmaf(v, wv2[d], a2);
    }
    al_e1[e0 + tid] = a1;
    al_e2[e0 + tid] = a2;
  }
  float s1 = a1, s2 = a2;
#pragma unroll
  for (int o = 32; o; o >>= 1) { s1 += __shfl_xor(s1, o); s2 += __shfl_xor(s2, o); }
  int lane = tid & 63, wave = tid >> 6;
  if (lane == 0) { ws1[wave] = s1; ws2[wave] = s2; }
  __syncthreads();
  if (tid == 0) {
    atomicAdd(&al_e_sum[0], ws1[0] + ws1[1] + ws1[2] + ws1[3]);
    atomicAdd(&al_e_sum[1], ws2[0] + ws2[1] + ws2[2] + ws2[3]);
  }
}

__global__ void k_loop_e(const float* __restrict__ al_e_sum, float* __restrict__ loop_e, float invE)
{
  int t = threadIdx.x;
  if (t < 2) loop_e[t] = al_e_sum[t] * invE;
}

// ---------------- CSR build over dst ----------------
__global__ void k_count(const int* __restrict__ dst, int* __restrict__ counts, int E)
{
  int i = blockIdx.x * blockDim.x + threadIdx.x;
  int stride = gridDim.x * blockDim.x;
  for (; i < E; i += stride) atomicAdd(&counts[dst[i]], 1);
}

__global__ __launch_bounds__(1024) void k_scanA(const int* __restrict__ counts, int* __restrict__ tmp,
                                                int* __restrict__ chunk_sums, int n)
{
  __shared__ int sd[1024];
  int tid = threadIdx.x;
  int i = blockIdx.x * 1024 + tid;
  int v = (i < n) ? counts[i] : 0;
  sd[tid] = v;
  __syncthreads();
  for (int off = 1; off < 1024; off <<= 1) {
    int t = (tid >= off) ? sd[tid - off] : 0;
    __syncthreads();
    sd[tid] += t;
    __syncthreads();
  }
  if (i < n) tmp[i] = sd[tid] - v;   // exclusive
  if (tid == 1023) chunk_sums[blockIdx.x] = sd[1023];
}

__global__ void k_scanB(const int* __restrict__ chunk_sums, int* __restrict__ chunk_off,
                        int nchunks, int* __restrict__ row_off_end)
{
  if (threadIdx.x == 0) {
    int run = 0;
    for (int c = 0; c < nchunks; ++c) { chunk_off[c] = run; run += chunk_sums[c]; }
    *row_off_end = run;
  }
}

__global__ __launch_bounds__(1024) void k_scanC(const int* __restrict__ tmp, const int* __restrict__ chunk_off,
                                                int* __restrict__ row_off, int* __restrict__ cursor, int n)
{
  int i = blockIdx.x * 1024 + threadIdx.x;
  if (i < n) {
    int v = tmp[i] + chunk_off[blockIdx.x];
    row_off[i] = v;
    cursor[i] = v;
  }
}

// scatter CSR payload: edata[pos] = {src, dst, al_e1, al_e2}  (one 16B store)
__global__ void k_fill(const int* __restrict__ src, const int* __restrict__ dst,
                       const float* __restrict__ al_e1, const float* __restrict__ al_e2,
                       int* __restrict__ cursor, float4* __restrict__ edata, int E)
{
  int i = blockIdx.x * blockDim.x + threadIdx.x;
  int stride = gridDim.x * blockDim.x;
  for (; i < E; i += stride) {
    int d = dst[i];
    int pos = atomicAdd(&cursor[d], 1);
    float4 v;
    v.x = __int_as_float(src[i]);
    v.y = __int_as_float(d);
    v.z = al_e1[i];
    v.w = al_e2[i];
    edata[pos] = v;
  }
}

// ---------------- h16[M,128](fp16) = A[M,128] @ W[128,128]  + fused al_s/al_d ----
// 32 rows/block, 4x4 register tile per thread, W staged in LDS. No fp32 C output.
__global__ __launch_bounds__(256) void k_gemm128(const float* __restrict__ A,
                                                 const float* __restrict__ W,
                                                 unsigned int* __restrict__ h16, // N x 64 uints (half2)
                                                 const float* __restrict__ a_s,
                                                 const float* __restrict__ a_d,
                                                 float* __restrict__ al_s,
                                                 float* __restrict__ al_d,
                                                 int M)
{
  __shared__ float Wl[HD * HD];
  int tid = threadIdx.x;
  {
    const float4* W4 = (const float4*)W;
    float4* Wl4 = (float4*)Wl;
#pragma unroll
    for (int i = 0; i < 16; ++i) Wl4[tid + i * 256] = W4[tid + i * 256];
  }
  __syncthreads();

  int q = tid & 31;        // column quad: cols 4q..4q+3
  int rg = tid >> 5;       // row group 0..7, 4 rows each -> 32 rows/block
  int row0 = blockIdx.x * 32 + rg * 4;

  const float* xr0 = A + (size_t)(row0 + 0 < M ? row0 + 0 : M - 1) * HD;
  const float* xr1 = A + (size_t)(row0 + 1 < M ? row0 + 1 : M - 1) * HD;
  const float* xr2 = A + (size_t)(row0 + 2 < M ? row0 + 2 : M - 1) * HD;
  const float* xr3 = A + (size_t)(row0 + 3 < M ? row0 + 3 : M - 1) * HD;

  float4 acc0 = {0.f,0.f,0.f,0.f}, acc1 = acc0, acc2 = acc0, acc3 = acc0;

  for (int k = 0; k < HD; k += 4) {
    const float* wk = &Wl[k * HD + 4 * q];
    float4 w0 = *(const float4*)(wk);
    float4 w1 = *(const float4*)(wk + HD);
    float4 w2 = *(const float4*)(wk + 2 * HD);
    float4 w3 = *(const float4*)(wk + 3 * HD);
    float4 xa = *(const float4*)(xr0 + k);
    float4 xb = *(const float4*)(xr1 + k);
    float4 xc = *(const float4*)(xr2 + k);
    float4 xd = *(const float4*)(xr3 + k);
#define ROWFMA(ACC, XV)                                                   \
    ACC.x = fmaf(XV.x, w0.x, ACC.x); ACC.x = fmaf(XV.y, w1.x, ACC.x);     \
    ACC.x = fmaf(XV.z, w2.x, ACC.x); ACC.x = fmaf(XV.w, w3.x, ACC.x);     \
    ACC.y = fmaf(XV.x, w0.y, ACC.y); ACC.y = fmaf(XV.y, w1.y, ACC.y);     \
    ACC.y = fmaf(XV.z, w2.y, ACC.y); ACC.y = fmaf(XV.w, w3.y, ACC.y);     \
    ACC.z = fmaf(XV.x, w0.z, ACC.z); ACC.z = fmaf(XV.y, w1.z, ACC.z);     \
    ACC.z = fmaf(XV.z, w2.z, ACC.z); ACC.z = fmaf(XV.w, w3.z, ACC.z);     \
    ACC.w = fmaf(XV.x, w0.w, ACC.w); ACC.w = fmaf(XV.y, w1.w, ACC.w);     \
    ACC.w = fmaf(XV.z, w2.w, ACC.w); ACC.w = fmaf(XV.w, w3.w, ACC.w);
    ROWFMA(acc0, xa)
    ROWFMA(acc1, xb)
    ROWFMA(acc2, xc)
    ROWFMA(acc3, xd)
#undef ROWFMA
  }

  // fp16 store: cols 4q..4q+3 as two half2 packed in a uint2 (8B per row)
  {
    uint2 v;
    if (row0 + 0 < M) { v.x = pack_h2(acc0.x, acc0.y); v.y = pack_h2(acc0.z, acc0.w);
      *(uint2*)&h16[(size_t)(row0 + 0) * 64 + 2 * q] = v; }
    if (row0 + 1 < M) { v.x = pack_h2(acc1.x, acc1.y); v.y = pack_h2(acc1.z, acc1.w);
      *(uint2*)&h16[(size_t)(row0 + 1) * 64 + 2 * q] = v; }
    if (row0 + 2 < M) { v.x = pack_h2(acc2.x, acc2.y); v.y = pack_h2(acc2.z, acc2.w);
      *(uint2*)&h16[(size_t)(row0 + 2) * 64 + 2 * q] = v; }
    if (row0 + 3 < M) { v.x = pack_h2(acc3.x, acc3.y); v.y = pack_h2(acc3.z, acc3.w);
      *(uint2*)&h16[(size_t)(row0 + 3) * 64 + 2 * q] = v; }
  }

  // fused node dots (fp32 accs -> exact): al_s/al_d
  float4 asv = *(const float4*)&a_s[4 * q];
  float4 adv = *(const float4*)&a_d[4 * q];
  float ps0 = acc0.x*asv.x + acc0.y*asv.y + acc0.z*asv.z + acc0.w*asv.w;
  float ps1 = acc1.x*asv.x + acc1.y*asv.y + acc1.z*asv.z + acc1.w*asv.w;
  float ps2 = acc2.x*asv.x + acc2.y*asv.y + acc2.z*asv.z + acc2.w*asv.w;
  float ps3 = acc3.x*asv.x + acc3.y*asv.y + acc3.z*asv.z + acc3.w*asv.w;
  float pd0 = acc0.x*adv.x + acc0.y*adv.y + acc0.z*adv.z + acc0.w*adv.w;
  float pd1 = acc1.x*adv.x + acc1.y*adv.y + acc1.z*adv.z + acc1.w*adv.w;
  float pd2 = acc2.x*adv.x + acc2.y*adv.y + acc2.z*adv.z + acc2.w*adv.w;
  float pd3 = acc3.x*adv.x + acc3.y*adv.y + acc3.z*adv.z + acc3.w*adv.w;
#pragma unroll
  for (int o = 16; o; o >>= 1) {
    ps0 += __shfl_xor(ps0, o); ps1 += __shfl_xor(ps1, o);
    ps2 += __shfl_xor(ps2, o); ps3 += __shfl_xor(ps3, o);
    pd0 += __shfl_xor(pd0, o); pd1 += __shfl_xor(pd1, o);
    pd2 += __shfl_xor(pd2, o); pd3 += __shfl_xor(pd3, o);
  }
  if (q == 0) {
    if (row0 + 0 < M) { al_s[row0 + 0] = ps0; al_d[row0 + 0] = pd0; }
    if (row0 + 1 < M) { al_s[row0 + 1] = ps1; al_d[row0 + 1] = pd1; }
    if (row0 + 2 < M) { al_s[row0 + 2] = ps2; al_d[row0 + 2] = pd2; }
    if (row0 + 3 < M) { al_s[row0 + 3] = ps3; al_d[row0 + 3] = pd3; }
  }
}

// ---------------- per-edge attention weight (CSR order, coalesced) ----------
__global__ __launch_bounds__(256) void k_edge_w(
    const float4* __restrict__ edata, const float* __restrict__ al_s,
    const float* __restrict__ al_d, float2* __restrict__ pack, int E, int layer)
{
  int k = blockIdx.x * 256 + threadIdx.x;
  if (k >= E) return;
  float4 v = edata[k];
  int sn = __float_as_int(v.x);
  int dn = __float_as_int(v.y);
  float ale = layer ? v.w : v.z;
  float a = al_s[sn] + al_d[dn] + ale;
  a = a > 0.f ? a : NEG_SLOPE * a;
  pack[k] = make_float2(v.x, __expf(a));
}

// ---------------- GAT aggregation: one wave per dst node, fp16 h gathers ----
// Lane owns cols {2*lane, 2*lane+1}: one 4B (half2) load per edge per lane.
template <bool FUSE>
__global__ __launch_bounds__(256) void k_agg(
    const int* __restrict__ row_off, const float2* __restrict__ pack,
    const float* __restrict__ al_s, const float* __restrict__ al_d,
    const float* __restrict__ loop_e, int le_idx,
    const unsigned int* __restrict__ h16, const float* __restrict__ bias,
    float* __restrict__ o,
    const float* __restrict__ Wfc, const int* __restrict__ batchv,
    float* __restrict__ pool_sum, float* __restrict__ pool_cnt,
    int n_nodes)
{
  int wave = threadIdx.x >> 6, lane = threadIdx.x & 63;
  int n = blockIdx.x * 4 + wave;
  if (n >= n_nodes) return;

  // self loop; alphas are O(1): exp without max-shift is safe
  float a0 = al_s[n] + al_d[n] + loop_e[le_idx];
  a0 = a0 > 0.f ? a0 : NEG_SLOPE * a0;
  float w = __expf(a0);
  float2 hn = unpack_h2(h16[(size_t)n * 64 + lane]);
  float accx = w * hn.x;
  float accy = w * hn.y;
  float s = w;

  int k0 = row_off[n];
  int cnt = row_off[n + 1] - k0;
  const float2* pk = pack + k0;
  int k = 0;
  for (; k + 8 <= cnt; k += 8) {
    float2 p0 = pk[k+0], p1 = pk[k+1], p2 = pk[k+2], p3 = pk[k+3];
    float2 p4 = pk[k+4], p5 = pk[k+5], p6 = pk[k+6], p7 = pk[k+7];
    unsigned int g0 = h16[(size_t)__float_as_int(p0.x) * 64 + lane];
    unsigned int g1 = h16[(size_t)__float_as_int(p1.x) * 64 + lane];
    unsigned int g2 = h16[(size_t)__float_as_int(p2.x) * 64 + lane];
    unsigned int g3 = h16[(size_t)__float_as_int(p3.x) * 64 + lane];
    unsigned int g4 = h16[(size_t)__float_as_int(p4.x) * 64 + lane];
    unsigned int g5 = h16[(size_t)__float_as_int(p5.x) * 64 + lane];
    unsigned int g6 = h16[(size_t)__float_as_int(p6.x) * 64 + lane];
    unsigned int g7 = h16[(size_t)__float_as_int(p7.x) * 64 + lane];
    s += p0.y + p1.y + p2.y + p3.y + p4.y + p5.y + p6.y + p7.y;
#define ACCUM(P, GG) { float2 f = unpack_h2(GG); accx = fmaf(P.y, f.x, accx); accy = fmaf(P.y, f.y, accy); }
    ACCUM(p0, g0) ACCUM(p1, g1) ACCUM(p2, g2) ACCUM(p3, g3)
    ACCUM(p4, g4) ACCUM(p5, g5) ACCUM(p6, g6) ACCUM(p7, g7)
#undef ACCUM
  }
  for (; k < cnt; ++k) {
    float2 p = pk[k];
    unsigned int g = h16[(size_t)__float_as_int(p.x) * 64 + lane];
    s += p.y;
    float2 f = unpack_h2(g);
    accx = fmaf(p.y, f.x, accx);
    accy = fmaf(p.y, f.y, accy);
  }

  float inv = 1.0f / s;
  float2 bv = ((const float2*)bias)[lane];
  float o1v = fmaxf(accx * inv + bv.x, 0.f);
  float o2v = fmaxf(accy * inv + bv.y, 0.f);

  if (FUSE) {
    float2 wv = ((const float2*)Wfc)[lane];
    float t = o1v * wv.x + o2v * wv.y;
#pragma unroll
    for (int ofs = 32; ofs; ofs >>= 1) t += __shfl_xor(t, ofs);
    if (lane == 0) {
      int g = batchv[n];
      atomicAdd(&pool_sum[g], t);
      atomicAdd(&pool_cnt[g], 1.0f);
    }
  } else {
    float2* orow = (float2*)(o + (size_t)n * HD);
    orow[lane] = make_float2(o1v, o2v);
  }
}

// ---------------- finalize ----------------
__global__ void k_final(const float* __restrict__ pool_sum, const float* __restrict__ pool_cnt,
                        const float* __restrict__ bfc, float* __restrict__ out, int g)
{
  int i = blockIdx.x * blockDim.x + threadIdx.x;
  if (i < g) out[i] = pool_sum[i] / fmaxf(pool_cnt[i], 1.f) + bfc[0];
}

// =====================================================================
extern "C" void kernel_launch(void* const* d_in, const int* in_sizes, int n_in,
                              void* d_out, int out_size, void* d_ws, size_t ws_size,
                              hipStream_t stream)
{
  const float* x       = (const float*)d_in[0];
  const int*   ei      = (const int*)d_in[1];
  const float* ea      = (const float*)d_in[2];
  const int*   batchv  = (const int*)d_in[3];
  const float* W1  = (const float*)d_in[4];
  const float* as1 = (const float*)d_in[5];
  const float* ad1 = (const float*)d_in[6];
  const float* We1 = (const float*)d_in[7];
  const float* ae1 = (const float*)d_in[8];
  const float* b1  = (const float*)d_in[9];
  const float* W2  = (const float*)d_in[10];
  const float* as2 = (const float*)d_in[11];
  const float* ad2 = (const float*)d_in[12];
  const float* We2 = (const float*)d_in[13];
  const float* ae2 = (const float*)d_in[14];
  const float* b2  = (const float*)d_in[15];
  const float* Wfc = (const float*)d_in[16];
  const float* bfc = (const float*)d_in[17];
  float* out = (float*)d_out;

  const int N = in_sizes[0] / HD;
  const int E = in_sizes[1] / 2;
  const int G = out_size;               // 256 graphs, OUT=1
  const int* src = ei;
  const int* dst = ei + E;

  // ---- carve workspace ----
  char* p = (char*)d_ws;
  auto alloc = [&](size_t bytes) -> void* {
    void* r = (void*)p;
    p += (bytes + 255) & ~(size_t)255;
    return r;
  };
  unsigned int* h16 = (unsigned int*)alloc((size_t)N * 64 * 4); // fp16 h (half2 x64)
  float*  oB       = (float*)alloc((size_t)N * HD * 4);   // relu(gat1), fp32 GEMM2 input
  float*  al_e1    = (float*)alloc((size_t)E * 4);
  float*  al_e2    = (float*)alloc((size_t)E * 4);
  float*  al_s     = (float*)alloc((size_t)N * 4);
  float*  al_d     = (float*)alloc((size_t)N * 4);
  int*    counts   = (int*)alloc((size_t)N * 4);          // then reused as cursor
  int*    row_off  = (int*)alloc((size_t)(N + 1) * 4);
  int*    tmp_scan = (int*)alloc((size_t)N * 4);
  int*    chunk_sums = (int*)alloc(64 * 4);
  int*    chunk_off  = (int*)alloc(64 * 4);
  float4* edata    = (float4*)alloc((size_t)E * 16);      // CSR payload {src,dst,ale1,ale2}
  float2* pack     = (float2*)alloc((size_t)E * 8);       // per-layer {src, w}
  float*  we_vec   = (float*)alloc(2 * 64 * 4);
  float*  al_e_sum = (float*)alloc(2 * 4);
  float*  loop_e   = (float*)alloc(2 * 4);
  float*  pool_sum = (float*)alloc((size_t)G * 4);
  float*  pool_cnt = (float*)alloc((size_t)G * 4);
  (void)ws_size; (void)n_in;

  const int nchunks = ceil_div(N, 1024);

  k_init<<<ceil_div(N, 256), 256, 0, stream>>>(counts, pool_sum, pool_cnt, al_e_sum, N, G);
  k_wevec<<<2, 64, 0, stream>>>(We1, ae1, We2, ae2, we_vec);
  k_edge_ale<<<ceil_div(E, 256), 256, 0, stream>>>(ea, we_vec, al_e1, al_e2, al_e_sum, E);
  k_loop_e<<<1, 64, 0, stream>>>(al_e_sum, loop_e, 1.0f / (float)E);
  k_count<<<2048, 256, 0, stream>>>(dst, counts, E);
  k_scanA<<<nchunks, 1024, 0, stream>>>(counts, tmp_scan, chunk_sums, N);
  k_scanB<<<1, 64, 0, stream>>>(chunk_sums, chunk_off, nchunks, &row_off[N]);
  k_scanC<<<nchunks, 1024, 0, stream>>>(tmp_scan, chunk_off, row_off, counts, N);
  k_fill<<<2048, 256, 0, stream>>>(src, dst, al_e1, al_e2, counts, edata, E);

  // ---- layer 1 ----
  k_gemm128<<<ceil_div(N, 32), 256, 0, stream>>>(x, W1, h16, as1, ad1, al_s, al_d, N);
  k_edge_w<<<ceil_div(E, 256), 256, 0, stream>>>(edata, al_s, al_d, pack, E, 0);
  k_agg<false><<<ceil_div(N, 4), 256, 0, stream>>>(row_off, pack, al_s, al_d,
      loop_e, 0, h16, b1, oB, nullptr, nullptr, nullptr, nullptr, N);

  // ---- layer 2 (pooling fused into epilogue) ----
  k_gemm128<<<ceil_div(N, 32), 256, 0, stream>>>(oB, W2, h16, as2, ad2, al_s, al_d, N);
  k_edge_w<<<ceil_div(E, 256), 256, 0, stream>>>(edata, al_s, al_d, pack, E, 1);
  k_agg<true><<<ceil_div(N, 4), 256, 0, stream>>>(row_off, pack, al_s, al_d,
      loop_e, 1, h16, b2, nullptr, Wfc, batchv, pool_sum, pool_cnt, N);

  k_final<<<1, 256, 0, stream>>>(pool_sum, pool_cnt, bfc, out, G);
}